// Round 19
// baseline (69.116 us; speedup 1.0000x reference)
//
#include <hip/hip_runtime.h>

#define DIM     400
#define NENT    14541
#define B       32
#define NCAND   14505
#define THREADS 256
#define NTILE   1818      // ceil(NENT/8)
#define NSC     1814      // ceil(NCAND/8) outputs per scatter chunk

// ---- phase 1: entity-major scores. stab[b][e] = 0.98*sum(max(|c-q|,o)) + 0.02*sum(|c-q|)
// block = tile of 8 entities x all 32 batches; 512 thr = 8 waves; wave = 4 batch-slots
// x 16 dim-lanes (lane u owns dims [25u, 25u+25) of its slot's batch).
// Entity rows read SEQUENTIALLY from global (no gather, no conversion); the 4 slots
// broadcast-read the same row -> L1 amplification is 8 waves, not 32 batches (~186MB L1).
// q/o register-resident (50 f32). No LDS, no atomics, no setup dependency.
__global__ __launch_bounds__(512, 2)
void score_ent(const float* __restrict__ ent,
               const float* __restrict__ relc,
               const float* __restrict__ relo,
               const int*   __restrict__ pairs,
               float* __restrict__ stab) {
    const int tile = blockIdx.x;
    const int e0   = tile * 8;
    const int tid  = threadIdx.x;
    const int wid  = tid >> 6;
    const int lane = tid & 63;
    const int u    = lane & 15;          // dim-lane: dims [25u, 25u+25)
    const int g    = lane >> 4;          // batch slot
    const int b    = 4 * wid + g;        // 0..31

    const int hd = pairs[2 * b + 0];
    const int rl = pairs[2 * b + 1];
    const float* hp = ent  + (size_t)hd * DIM + 25 * u;
    const float* cp = relc + (size_t)rl * DIM + 25 * u;
    const float* op = relo + (size_t)rl * DIM + 25 * u;

    float q[25], o[25];
#pragma unroll
    for (int k = 0; k < 25; ++k) {
        q[k] = hp[k] + cp[k];
        o[k] = op[k];
    }

    const int emax = (NENT - e0 < 8) ? (NENT - e0) : 8;
    for (int c = 0; c < emax; ++c) {
        const float* cr = ent + (size_t)(e0 + c) * DIM + 25 * u;
        float am = 0.f, ad = 0.f;
#pragma unroll
        for (int k = 0; k < 25; ++k) {
            float d = cr[k] - q[k];
            float a = fabsf(d);
            am += fmaxf(a, o[k]);
            ad += a;
        }
        float s = fmaf(0.98f, am, 0.02f * ad);
        s += __shfl_xor(s, 1);
        s += __shfl_xor(s, 2);
        s += __shfl_xor(s, 4);
        s += __shfl_xor(s, 8);           // sum over 16 dim-lanes
        if (u == 0)
            stab[(size_t)b * NENT + e0 + c] = s;
    }
}

// ---- phase 2: scatter. out[b][n] = base[b] - stab[b][cidx[n]].
// stab is 1.86 MB -> fits every XCD L2; gather is 4B from a hot table.
__global__ __launch_bounds__(THREADS)
void scatter_k(const float* __restrict__ stab,
               const float* __restrict__ relo,
               const float* __restrict__ onev,
               const int*   __restrict__ pairs,
               const int*   __restrict__ cidx,
               float* __restrict__ out) {
    const int blk = blockIdx.x;          // 32 batches x 8 chunks
    const int b   = blk >> 3;
    const int ch  = blk & 7;
    const int tid = threadIdx.x;

    // base[b] = one + 0.98 * sum(relo[r]) (redundant per chunk; L2-hot)
    const int rl = pairs[2 * b + 1];
    float so = 0.f;
    if (tid < 100) {
        float4 v = ((const float4*)(relo + (size_t)rl * DIM))[tid];
        so = v.x + v.y + v.z + v.w;
    }
    for (int off = 32; off; off >>= 1) so += __shfl_down(so, off);
    __shared__ float red[4];
    if ((tid & 63) == 0) red[tid >> 6] = so;
    __syncthreads();
    const float base = onev[0] + 0.98f * (red[0] + red[1] + red[2] + red[3]);

    const float* sb = stab + (size_t)b * NENT;
    const int n0 = ch * NSC;
    const int n1 = (n0 + NSC < NCAND) ? n0 + NSC : NCAND;
    for (int n = n0 + tid; n < n1; n += THREADS) {
        const int ci = cidx[n];
        out[(size_t)b * NCAND + n] = base - sb[ci];
    }
}

// ---- fallback (no ws): R9 f32 kernel verbatim ----
__global__ __launch_bounds__(THREADS, 2)
void score_f32(const float* __restrict__ ent,
               const float* __restrict__ relc,
               const float* __restrict__ relo,
               const float* __restrict__ onev,
               const int*   __restrict__ pairs,
               const int*   __restrict__ cidx,
               float* __restrict__ out) {
    const int fid  = blockIdx.x;
    const int xcd  = fid & 7;
    const int rest = fid >> 3;
    const int bq   = rest & 7;
    const int tc   = rest >> 3;
    const int t    = xcd + 8 * tc;

    const int tid  = threadIdx.x;
    const int lane = tid & 63;
    const int u    = lane & 15;
    const int g    = lane >> 4;
    const int b    = __builtin_amdgcn_readfirstlane(bq * 4 + (tid >> 6));

    const int hd = pairs[b * 2 + 0];
    const int rl = pairs[b * 2 + 1];
    const float4* hb = (const float4*)(ent  + (size_t)hd * DIM) + u;
    const float4* cb = (const float4*)(relc + (size_t)rl * DIM) + u;
    const float4* ob = (const float4*)(relo + (size_t)rl * DIM) + u;

    float4 q[7], o[7];
    float oa = 0.f;
#pragma unroll
    for (int k = 0; k < 6; ++k) {
        float4 h = hb[16 * k], c = cb[16 * k];
        q[k] = make_float4(h.x + c.x, h.y + c.y, h.z + c.z, h.w + c.w);
        o[k] = ob[16 * k];
        oa += o[k].x + o[k].y + o[k].z + o[k].w;
    }
    if (u < 4) {
        float4 h = hb[96], c = cb[96];
        q[6] = make_float4(h.x + c.x, h.y + c.y, h.z + c.z, h.w + c.w);
        o[6] = ob[96];
        oa += o[6].x + o[6].y + o[6].z + o[6].w;
    }
    oa += __shfl_xor(oa, 1);
    oa += __shfl_xor(oa, 2);
    oa += __shfl_xor(oa, 4);
    oa += __shfl_xor(oa, 8);
    const float base = onev[0] + 0.98f * oa;

    const float4* entu = (const float4*)ent + u;

#define E(vc, vq, vo, AM, AD)                     \
        {                                         \
            float d_ = (vc) - (vq);               \
            AM += fmaxf(fabsf(d_), (vo));         \
            AD += fabsf(d_);                      \
        }
#define F4(k, AM, AD)                             \
        E(cbuf[k].x, q[k].x, o[k].x, AM, AD)      \
        E(cbuf[k].y, q[k].y, o[k].y, AM, AD)      \
        E(cbuf[k].z, q[k].z, o[k].z, AM, AD)      \
        E(cbuf[k].w, q[k].w, o[k].w, AM, AD)

    for (int rr = t; rr < 3627; rr += 256) {
        const int cand = 4 * rr + g;
        const int ci   = cidx[cand < NCAND ? cand : NCAND - 1];
        const float4* p = entu + (size_t)ci * 100;

        float4 cbuf[7];
#pragma unroll
        for (int k = 0; k < 6; ++k) cbuf[k] = p[16 * k];
        if (u < 4) cbuf[6] = p[96];

        float am0 = 0.f, ad0 = 0.f, am1 = 0.f, ad1 = 0.f;
        F4(0, am0, ad0) F4(1, am1, ad1)
        F4(2, am0, ad0) F4(3, am1, ad1)
        F4(4, am0, ad0) F4(5, am1, ad1)
        if (u < 4) { F4(6, am0, ad0) }

        float s_ = fmaf(-0.98f, am0 + am1, -0.02f * (ad0 + ad1));
        s_ += __shfl_xor(s_, 1);
        s_ += __shfl_xor(s_, 2);
        s_ += __shfl_xor(s_, 4);
        s_ += __shfl_xor(s_, 8);

        if (u == 0 && cand < NCAND)
            out[(size_t)b * NCAND + cand] = base + s_;
    }
#undef F4
#undef E
}

extern "C" void kernel_launch(void* const* d_in, const int* in_sizes, int n_in,
                              void* d_out, int out_size, void* d_ws, size_t ws_size,
                              hipStream_t stream) {
    const float* ent   = (const float*)d_in[0];
    const float* relc  = (const float*)d_in[1];
    const float* relo  = (const float*)d_in[2];
    const float* onev  = (const float*)d_in[3];
    const int*   pairs = (const int*)d_in[4];
    const int*   cidx  = (const int*)d_in[5];
    float*       out   = (float*)d_out;

    const size_t need = (size_t)B * NENT * sizeof(float);   // 1.86 MB

    if (ws_size >= need) {
        float* stab = (float*)d_ws;
        score_ent<<<NTILE, 512, 0, stream>>>(ent, relc, relo, pairs, stab);
        scatter_k<<<B * 8, THREADS, 0, stream>>>(stab, relo, onev, pairs, cidx, out);
    } else {
        score_f32<<<8 * 8 * 32, THREADS, 0, stream>>>(
            ent, relc, relo, onev, pairs, cidx, out);
    }
}

// Round 20
// 39.842 us; speedup vs baseline: 1.7348x; 1.7348x over previous
//
#include <hip/hip_runtime.h>

#define DIM     400
#define NENT    14541
#define B       32
#define NCAND   14505
#define NSTRIP  303       // strips of 12 rounds: 303*12=3636 >= 3627 rounds
#define DROWS   14544     // 4*3636 rows in padded dense table
#define CVTN    (DROWS * 50)                       // 727200 uint4
#define CVTBLK  ((CVTN + 255) / 256)               // 2841
#define THREADS 256

typedef __attribute__((ext_vector_type(2))) _Float16 half2_t;

static __device__ __forceinline__ half2_t bch(unsigned u) {
    return __builtin_bit_cast(half2_t, u);
}
static __device__ __forceinline__ half2_t habs2(half2_t x) {
    unsigned u = __builtin_bit_cast(unsigned, x) & 0x7fff7fffu;
    return __builtin_bit_cast(half2_t, u);
}
static __device__ __forceinline__ unsigned pkh(float x, float y) {
    half2_t h;
    h.x = (_Float16)x;
    h.y = (_Float16)y;
    return __builtin_bit_cast(unsigned, h);
}
static __device__ __forceinline__ float dot2acc(half2_t m, float s) {
#if __has_builtin(__builtin_amdgcn_fdot2)
    const half2_t ones = {(_Float16)1.f, (_Float16)1.f};
    return __builtin_amdgcn_fdot2(m, ones, s, false);
#else
    return s + (float)m.x + (float)m.y;
#endif
}

// ---- merged setup: blocks [0,CVTBLK) dense16[n] = f16(ent[cidx[n]]) (gather ONCE);
// blocks [CVTBLK, CVTBLK+32): q16/o16/base prep.
__global__ void setup_kernel(const float* __restrict__ ent,
                             const float* __restrict__ relc,
                             const float* __restrict__ relo,
                             const float* __restrict__ onev,
                             const int*   __restrict__ pairs,
                             const int*   __restrict__ cidx,
                             uint4* __restrict__ dense16,
                             _Float16* __restrict__ q16,
                             _Float16* __restrict__ o16,
                             float* __restrict__ baseg) {
    const int blk = blockIdx.x;
    const int tid = threadIdx.x;
    if (blk < CVTBLK) {
        int i = blk * THREADS + tid;              // uint4 index: row*50 + col
        if (i >= CVTN) return;
        int row = i / 50;
        int col = i - row * 50;
        int n  = row < NCAND ? row : NCAND - 1;   // pad rows dup last cand
        int ci = cidx[n];
        const float4* s4 = (const float4*)(ent + (size_t)ci * DIM) + col * 2;
        float4 a = s4[0], c = s4[1];
        uint4 d;
        d.x = pkh(a.x, a.y);
        d.y = pkh(a.z, a.w);
        d.z = pkh(c.x, c.y);
        d.w = pkh(c.z, c.w);
        dense16[i] = d;
    } else {
        const int b = blk - CVTBLK;
        const int h = pairs[2 * b + 0];
        const int r = pairs[2 * b + 1];
        float so = 0.f;
        for (int i = tid; i < DIM; i += THREADS) {
            float qv = ent[(size_t)h * DIM + i] + relc[(size_t)r * DIM + i];
            float ov = relo[(size_t)r * DIM + i];
            q16[(size_t)b * DIM + i] = (_Float16)qv;
            o16[(size_t)b * DIM + i] = (_Float16)(0.98f * ov);
            so += ov;
        }
        __shared__ float sred[4];
        for (int off = 32; off; off >>= 1) so += __shfl_down(so, off);
        if ((tid & 63) == 0) sred[tid >> 6] = so;
        __syncthreads();
        if (tid == 0)
            baseg[b] = onev[0] + 0.98f * (sred[0] + sred[1] + sred[2] + sred[3]);
    }
}

// ---- main: 1 batch/wave, THREE quad-streams/iter over dense f16 table ----
// wave = 4 cand-slots x 16 dim-lanes; lane u owns uint4-cols {u,u+16,u+32} + 48+u (u<2).
// Strip owns rounds [12s, 12s+12) -> 4 iterations x 3 streams (no tail). Streams are
// contiguous (pB=pA+200, pC=pA+400): cheap addressing + spatial L2 locality.
// MLP: ~9.4 loads in flight/wave x 4 waves/SIMD = 37 -> covers ~200cy L2 latency
// (Little's law needs ~41; R17's 2 streams gave only 24 -> the 1.7x stretch).
__global__ __launch_bounds__(THREADS, 2)
void score_f16(const uint4* __restrict__ dense16,
               const uint4* __restrict__ q16,
               const uint4* __restrict__ o16,
               const float* __restrict__ baseg,
               float* __restrict__ out) {
    const int fid  = blockIdx.x;
    const int xcd  = fid & 7;
    const int rest = fid >> 3;
    const int bq   = rest & 7;           // 4-batch group
    const int tc   = rest >> 3;          // 0..37
    const int strip = xcd + 8 * tc;      // 0..303; 8 bq-blocks share this XCD
    if (strip >= NSTRIP) return;

    const int r0 = strip * 12;
    const int r1 = r0 + 12;

    const int tid  = threadIdx.x;
    const int wid  = tid >> 6;
    const int lane = tid & 63;
    const int u    = lane & 15;
    const int g    = lane >> 4;
    const int b    = __builtin_amdgcn_readfirstlane(4 * bq + wid);

    const uint4* qa = q16 + (size_t)b * 50;
    const uint4* oa = o16 + (size_t)b * 50;
    uint4 q[4], o[4];
    q[0] = qa[u]; q[1] = qa[u + 16]; q[2] = qa[u + 32];
    o[0] = oa[u]; o[1] = oa[u + 16]; o[2] = oa[u + 32];
    q[3] = q[0]; o[3] = o[0];
    if (u < 2) { q[3] = qa[48 + u]; o[3] = oa[48 + u]; }
    const float base = baseg[b];

    const half2_t K002 = {(_Float16)0.02f, (_Float16)0.02f};

#define PAIR(cu, qu, ou, SS)                                    \
    {                                                           \
        half2_t cc_ = bch(cu), qq_ = bch(qu), oo_ = bch(ou);    \
        half2_t dd_ = cc_ - qq_;                                \
        half2_t aa_ = habs2(dd_);                               \
        half2_t ee_ = aa_ * K002 + oo_;                         \
        half2_t mm_ = __builtin_elementwise_max(aa_, ee_);      \
        SS = dot2acc(mm_, SS);                                  \
    }
#define PROC(C, Q, O, SA, SB)                                   \
    PAIR(C.x, Q.x, O.x, SA) PAIR(C.y, Q.y, O.y, SB)             \
    PAIR(C.z, Q.z, O.z, SA) PAIR(C.w, Q.w, O.w, SB)

    for (int rr = r0; rr < r1; rr += 3) {
        const uint4* pA = dense16 + (size_t)(4 * rr + g) * 50;
        const uint4* pB = pA + 200;      // quad rr+1 (4 rows ahead)
        const uint4* pC = pA + 400;      // quad rr+2

        uint4 av0 = pA[u], av1 = pA[u + 16], av2 = pA[u + 32];
        uint4 bv0 = pB[u], bv1 = pB[u + 16], bv2 = pB[u + 32];
        uint4 cv0 = pC[u], cv1 = pC[u + 16], cv2 = pC[u + 32];
        uint4 av3, bv3, cv3;
        if (u < 2) { av3 = pA[48 + u]; bv3 = pB[48 + u]; cv3 = pC[48 + u]; }

        float sA0 = 0.f, sA1 = 0.f, sB0 = 0.f, sB1 = 0.f, sC0 = 0.f, sC1 = 0.f;
        PROC(av0, q[0], o[0], sA0, sA1)
        PROC(av1, q[1], o[1], sA0, sA1)
        PROC(av2, q[2], o[2], sA0, sA1)
        if (u < 2) { PROC(av3, q[3], o[3], sA0, sA1) }
        PROC(bv0, q[0], o[0], sB0, sB1)
        PROC(bv1, q[1], o[1], sB0, sB1)
        PROC(bv2, q[2], o[2], sB0, sB1)
        if (u < 2) { PROC(bv3, q[3], o[3], sB0, sB1) }
        PROC(cv0, q[0], o[0], sC0, sC1)
        PROC(cv1, q[1], o[1], sC0, sC1)
        PROC(cv2, q[2], o[2], sC0, sC1)
        if (u < 2) { PROC(cv3, q[3], o[3], sC0, sC1) }

        float sA = sA0 + sA1;
        float sB = sB0 + sB1;
        float sC = sC0 + sC1;
        sA += __shfl_xor(sA, 1); sB += __shfl_xor(sB, 1); sC += __shfl_xor(sC, 1);
        sA += __shfl_xor(sA, 2); sB += __shfl_xor(sB, 2); sC += __shfl_xor(sC, 2);
        sA += __shfl_xor(sA, 4); sB += __shfl_xor(sB, 4); sC += __shfl_xor(sC, 4);
        sA += __shfl_xor(sA, 8); sB += __shfl_xor(sB, 8); sC += __shfl_xor(sC, 8);

        if (u == 0) {
            const int candA = 4 * rr + g;
            if (candA < NCAND)     out[(size_t)b * NCAND + candA]     = base - sA;
            if (candA + 4 < NCAND) out[(size_t)b * NCAND + candA + 4] = base - sB;
            if (candA + 8 < NCAND) out[(size_t)b * NCAND + candA + 8] = base - sC;
        }
    }
#undef PROC
#undef PAIR
}

// ---- fallback (no ws): R9 f32 kernel verbatim ----
__global__ __launch_bounds__(THREADS, 2)
void score_f32(const float* __restrict__ ent,
               const float* __restrict__ relc,
               const float* __restrict__ relo,
               const float* __restrict__ onev,
               const int*   __restrict__ pairs,
               const int*   __restrict__ cidx,
               float* __restrict__ out) {
    const int fid  = blockIdx.x;
    const int xcd  = fid & 7;
    const int rest = fid >> 3;
    const int bq   = rest & 7;
    const int tc   = rest >> 3;
    const int t    = xcd + 8 * tc;

    const int tid  = threadIdx.x;
    const int lane = tid & 63;
    const int u    = lane & 15;
    const int g    = lane >> 4;
    const int b    = __builtin_amdgcn_readfirstlane(bq * 4 + (tid >> 6));

    const int hd = pairs[b * 2 + 0];
    const int rl = pairs[b * 2 + 1];
    const float4* hb = (const float4*)(ent  + (size_t)hd * DIM) + u;
    const float4* cb = (const float4*)(relc + (size_t)rl * DIM) + u;
    const float4* ob = (const float4*)(relo + (size_t)rl * DIM) + u;

    float4 q[7], o[7];
    float oa = 0.f;
#pragma unroll
    for (int k = 0; k < 6; ++k) {
        float4 h = hb[16 * k], c = cb[16 * k];
        q[k] = make_float4(h.x + c.x, h.y + c.y, h.z + c.z, h.w + c.w);
        o[k] = ob[16 * k];
        oa += o[k].x + o[k].y + o[k].z + o[k].w;
    }
    if (u < 4) {
        float4 h = hb[96], c = cb[96];
        q[6] = make_float4(h.x + c.x, h.y + c.y, h.z + c.z, h.w + c.w);
        o[6] = ob[96];
        oa += o[6].x + o[6].y + o[6].z + o[6].w;
    }
    oa += __shfl_xor(oa, 1);
    oa += __shfl_xor(oa, 2);
    oa += __shfl_xor(oa, 4);
    oa += __shfl_xor(oa, 8);
    const float base = onev[0] + 0.98f * oa;

    const float4* entu = (const float4*)ent + u;

#define E(vc, vq, vo, AM, AD)                     \
        {                                         \
            float d_ = (vc) - (vq);               \
            AM += fmaxf(fabsf(d_), (vo));         \
            AD += fabsf(d_);                      \
        }
#define F4(k, AM, AD)                             \
        E(cbuf[k].x, q[k].x, o[k].x, AM, AD)      \
        E(cbuf[k].y, q[k].y, o[k].y, AM, AD)      \
        E(cbuf[k].z, q[k].z, o[k].z, AM, AD)      \
        E(cbuf[k].w, q[k].w, o[k].w, AM, AD)

    for (int rr = t; rr < 3627; rr += 256) {
        const int cand = 4 * rr + g;
        const int ci   = cidx[cand < NCAND ? cand : NCAND - 1];
        const float4* p = entu + (size_t)ci * 100;

        float4 cbuf[7];
#pragma unroll
        for (int k = 0; k < 6; ++k) cbuf[k] = p[16 * k];
        if (u < 4) cbuf[6] = p[96];

        float am0 = 0.f, ad0 = 0.f, am1 = 0.f, ad1 = 0.f;
        F4(0, am0, ad0) F4(1, am1, ad1)
        F4(2, am0, ad0) F4(3, am1, ad1)
        F4(4, am0, ad0) F4(5, am1, ad1)
        if (u < 4) { F4(6, am0, ad0) }

        float s_ = fmaf(-0.98f, am0 + am1, -0.02f * (ad0 + ad1));
        s_ += __shfl_xor(s_, 1);
        s_ += __shfl_xor(s_, 2);
        s_ += __shfl_xor(s_, 4);
        s_ += __shfl_xor(s_, 8);

        if (u == 0 && cand < NCAND)
            out[(size_t)b * NCAND + cand] = base + s_;
    }
#undef F4
#undef E
}

extern "C" void kernel_launch(void* const* d_in, const int* in_sizes, int n_in,
                              void* d_out, int out_size, void* d_ws, size_t ws_size,
                              hipStream_t stream) {
    const float* ent   = (const float*)d_in[0];
    const float* relc  = (const float*)d_in[1];
    const float* relo  = (const float*)d_in[2];
    const float* onev  = (const float*)d_in[3];
    const int*   pairs = (const int*)d_in[4];
    const int*   cidx  = (const int*)d_in[5];
    float*       out   = (float*)d_out;

    const size_t denB = (size_t)DROWS * DIM * 2;     // 11,635,200 B
    const size_t qB   = (size_t)B * DIM * 2;         // 25,600
    const size_t need = denB + 2 * qB + B * sizeof(float);

    if (ws_size >= need) {
        unsigned char* w = (unsigned char*)d_ws;
        uint4*    dense16 = (uint4*)w;
        _Float16* q16     = (_Float16*)(w + denB);
        _Float16* o16     = (_Float16*)(w + denB + qB);
        float*    baseg   = (float*)(w + denB + 2 * qB);

        setup_kernel<<<CVTBLK + B, THREADS, 0, stream>>>(
            ent, relc, relo, onev, pairs, cidx, dense16, q16, o16, baseg);
        score_f16<<<8 * 8 * 38, THREADS, 0, stream>>>(   // 2432 blocks (8 idle)
            dense16, (const uint4*)q16, (const uint4*)o16, baseg, out);
    } else {
        score_f32<<<8 * 8 * 32, THREADS, 0, stream>>>(
            ent, relc, relo, onev, pairs, cidx, out);
    }
}

// Round 21
// 37.191 us; speedup vs baseline: 1.8584x; 1.0713x over previous
//
#include <hip/hip_runtime.h>

#define DIM     400
#define NENT    14541
#define B       32
#define NCAND   14505
#define PAIRS   7280      // candidate pairs (table padded to 14560 rows)
#define DROWS   14560
#define CVTN    (DROWS * 50)                 // 728000 uint4
#define CVTBLK  ((CVTN + 255) / 256)         // 2844
#define SBLOCKS (PAIRS / 8)                  // 910 score blocks (8 pairs each)
#define THREADS 256

typedef __attribute__((ext_vector_type(2))) _Float16 half2_t;

static __device__ __forceinline__ half2_t bch(unsigned u) {
    return __builtin_bit_cast(half2_t, u);
}
static __device__ __forceinline__ half2_t habs2(half2_t x) {
    unsigned u = __builtin_bit_cast(unsigned, x) & 0x7fff7fffu;
    return __builtin_bit_cast(half2_t, u);
}
static __device__ __forceinline__ unsigned pkh(float x, float y) {
    half2_t h;
    h.x = (_Float16)x;
    h.y = (_Float16)y;
    return __builtin_bit_cast(unsigned, h);
}
static __device__ __forceinline__ float dot2acc(half2_t m, float s) {
#if __has_builtin(__builtin_amdgcn_fdot2)
    const half2_t ones = {(_Float16)1.f, (_Float16)1.f};
    return __builtin_amdgcn_fdot2(m, ones, s, false);
#else
    return s + (float)m.x + (float)m.y;
#endif
}

// ---- merged setup ----
// blocks [0,CVTBLK): dense16[row] = f16(ent[cidx[row]])  (gather once, rows>=NCAND dup)
// blocks [CVTBLK, CVTBLK+32): TRANSPOSED q/o: q16t[j*32+b] = uint4 of 8 f16 dims
// [8j,8j+8) of batch b; o16t likewise (pre-scaled 0.98); baseg[b].
__global__ void setup_kernel(const float* __restrict__ ent,
                             const float* __restrict__ relc,
                             const float* __restrict__ relo,
                             const float* __restrict__ onev,
                             const int*   __restrict__ pairs,
                             const int*   __restrict__ cidx,
                             uint4* __restrict__ dense16,
                             uint4* __restrict__ q16t,
                             uint4* __restrict__ o16t,
                             float* __restrict__ baseg) {
    const int blk = blockIdx.x;
    const int tid = threadIdx.x;
    if (blk < CVTBLK) {
        int i = blk * THREADS + tid;              // uint4 index: row*50 + col
        if (i >= CVTN) return;
        int row = i / 50;
        int col = i - row * 50;
        int n  = row < NCAND ? row : NCAND - 1;
        int ci = cidx[n];
        const float4* s4 = (const float4*)(ent + (size_t)ci * DIM) + col * 2;
        float4 a = s4[0], c = s4[1];
        uint4 d;
        d.x = pkh(a.x, a.y);
        d.y = pkh(a.z, a.w);
        d.z = pkh(c.x, c.y);
        d.w = pkh(c.z, c.w);
        dense16[i] = d;
    } else {
        const int b = blk - CVTBLK;
        const int h = pairs[2 * b + 0];
        const int r = pairs[2 * b + 1];
        float so = 0.f;
        if (tid < 50) {
            const float4* hp = (const float4*)(ent  + (size_t)h * DIM) + 2 * tid;
            const float4* cp = (const float4*)(relc + (size_t)r * DIM) + 2 * tid;
            const float4* op = (const float4*)(relo + (size_t)r * DIM) + 2 * tid;
            float4 h0 = hp[0], h1 = hp[1];
            float4 c0 = cp[0], c1 = cp[1];
            float4 v0 = op[0], v1 = op[1];
            uint4 qv, ov;
            qv.x = pkh(h0.x + c0.x, h0.y + c0.y);
            qv.y = pkh(h0.z + c0.z, h0.w + c0.w);
            qv.z = pkh(h1.x + c1.x, h1.y + c1.y);
            qv.w = pkh(h1.z + c1.z, h1.w + c1.w);
            ov.x = pkh(0.98f * v0.x, 0.98f * v0.y);
            ov.y = pkh(0.98f * v0.z, 0.98f * v0.w);
            ov.z = pkh(0.98f * v1.x, 0.98f * v1.y);
            ov.w = pkh(0.98f * v1.z, 0.98f * v1.w);
            q16t[tid * 32 + b] = qv;
            o16t[tid * 32 + b] = ov;
            so = v0.x + v0.y + v0.z + v0.w + v1.x + v1.y + v1.z + v1.w;
        }
        if (tid < 64) {
            so += __shfl_xor(so, 1);
            so += __shfl_xor(so, 2);
            so += __shfl_xor(so, 4);
            so += __shfl_xor(so, 8);
            so += __shfl_xor(so, 16);
            so += __shfl_xor(so, 32);
            if (tid == 0) baseg[b] = onev[0] + 0.98f * so;
        }
    }
}

// ---- main: candidate row read ONCE, all 32 batches applied from LDS ----
// Block = 4 waves, 8 pairs. LDS = q/o for ALL batches, transposed [chunk j][batch b]
// (51.2 KB). Wave = 2 cands x 32 batches: lane (c2,b) owns output (cand,b) fully —
// no reduce, no re-reads. Per chunk: 1 broadcast glb load (L2-sequential) +
// 2 conflict-free contiguous ds_read_b128 + 20 packed f16 VALU.
// Candidate global traffic: 372 MB (R14-R20) -> 11.6 MB.
__global__ __launch_bounds__(THREADS, 2)
void score_f16(const uint4* __restrict__ dense16,
               const uint4* __restrict__ q16t,
               const uint4* __restrict__ o16t,
               const float* __restrict__ baseg,
               float* __restrict__ out) {
    __shared__ uint4 qs[1600];           // [j][b] j=0..49, b=0..31
    __shared__ uint4 os[1600];
    const int tid = threadIdx.x;
    for (int i = tid; i < 1600; i += THREADS) {
        qs[i] = q16t[i];
        os[i] = o16t[i];
    }
    __syncthreads();

    const int wid  = tid >> 6;
    const int lane = tid & 63;
    const int b    = lane & 31;          // batch
    const int c2   = lane >> 5;          // candidate within pair
    const float base = baseg[b];

    const int p0 = blockIdx.x * 8 + wid * 2;   // 2 consecutive pairs per wave

    const half2_t K002 = {(_Float16)0.02f, (_Float16)0.02f};

#define PAIRE(cu, qu, ou, SS)                                   \
    {                                                           \
        half2_t cc_ = bch(cu), qq_ = bch(qu), oo_ = bch(ou);    \
        half2_t dd_ = cc_ - qq_;                                \
        half2_t aa_ = habs2(dd_);                               \
        half2_t ee_ = aa_ * K002 + oo_;                         \
        half2_t mm_ = __builtin_elementwise_max(aa_, ee_);      \
        SS = dot2acc(mm_, SS);                                  \
    }
#define PROC(C, Q, O, SA, SB)                                   \
    PAIRE(C.x, Q.x, O.x, SA) PAIRE(C.y, Q.y, O.y, SB)           \
    PAIRE(C.z, Q.z, O.z, SA) PAIRE(C.w, Q.w, O.w, SB)

#pragma unroll
    for (int pp = 0; pp < 2; ++pp) {
        const int pair = p0 + pp;
        const int cand = 2 * pair + c2;
        const uint4* cp = dense16 + (size_t)cand * 50;

        float s0 = 0.f, s1 = 0.f;
#pragma unroll 5
        for (int j = 0; j < 50; j += 2) {
            uint4 cj0 = cp[j];
            uint4 cj1 = cp[j + 1];
            uint4 qj0 = qs[j * 32 + b];
            uint4 oj0 = os[j * 32 + b];
            uint4 qj1 = qs[(j + 1) * 32 + b];
            uint4 oj1 = os[(j + 1) * 32 + b];
            PROC(cj0, qj0, oj0, s0, s1)
            PROC(cj1, qj1, oj1, s0, s1)
        }

        if (cand < NCAND)
            out[(size_t)b * NCAND + cand] = base - (s0 + s1);
    }
#undef PROC
#undef PAIRE
}

// ---- fallback (no ws): R9 f32 kernel verbatim ----
__global__ __launch_bounds__(THREADS, 2)
void score_f32(const float* __restrict__ ent,
               const float* __restrict__ relc,
               const float* __restrict__ relo,
               const float* __restrict__ onev,
               const int*   __restrict__ pairs,
               const int*   __restrict__ cidx,
               float* __restrict__ out) {
    const int fid  = blockIdx.x;
    const int xcd  = fid & 7;
    const int rest = fid >> 3;
    const int bq   = rest & 7;
    const int tc   = rest >> 3;
    const int t    = xcd + 8 * tc;

    const int tid  = threadIdx.x;
    const int lane = tid & 63;
    const int u    = lane & 15;
    const int g    = lane >> 4;
    const int b    = __builtin_amdgcn_readfirstlane(bq * 4 + (tid >> 6));

    const int hd = pairs[b * 2 + 0];
    const int rl = pairs[b * 2 + 1];
    const float4* hb = (const float4*)(ent  + (size_t)hd * DIM) + u;
    const float4* cb = (const float4*)(relc + (size_t)rl * DIM) + u;
    const float4* ob = (const float4*)(relo + (size_t)rl * DIM) + u;

    float4 q[7], o[7];
    float oa = 0.f;
#pragma unroll
    for (int k = 0; k < 6; ++k) {
        float4 h = hb[16 * k], c = cb[16 * k];
        q[k] = make_float4(h.x + c.x, h.y + c.y, h.z + c.z, h.w + c.w);
        o[k] = ob[16 * k];
        oa += o[k].x + o[k].y + o[k].z + o[k].w;
    }
    if (u < 4) {
        float4 h = hb[96], c = cb[96];
        q[6] = make_float4(h.x + c.x, h.y + c.y, h.z + c.z, h.w + c.w);
        o[6] = ob[96];
        oa += o[6].x + o[6].y + o[6].z + o[6].w;
    }
    oa += __shfl_xor(oa, 1);
    oa += __shfl_xor(oa, 2);
    oa += __shfl_xor(oa, 4);
    oa += __shfl_xor(oa, 8);
    const float base = onev[0] + 0.98f * oa;

    const float4* entu = (const float4*)ent + u;

#define E(vc, vq, vo, AM, AD)                     \
        {                                         \
            float d_ = (vc) - (vq);               \
            AM += fmaxf(fabsf(d_), (vo));         \
            AD += fabsf(d_);                      \
        }
#define F4(k, AM, AD)                             \
        E(cbuf[k].x, q[k].x, o[k].x, AM, AD)      \
        E(cbuf[k].y, q[k].y, o[k].y, AM, AD)      \
        E(cbuf[k].z, q[k].z, o[k].z, AM, AD)      \
        E(cbuf[k].w, q[k].w, o[k].w, AM, AD)

    for (int rr = t; rr < 3627; rr += 256) {
        const int cand = 4 * rr + g;
        const int ci   = cidx[cand < NCAND ? cand : NCAND - 1];
        const float4* p = entu + (size_t)ci * 100;

        float4 cbuf[7];
#pragma unroll
        for (int k = 0; k < 6; ++k) cbuf[k] = p[16 * k];
        if (u < 4) cbuf[6] = p[96];

        float am0 = 0.f, ad0 = 0.f, am1 = 0.f, ad1 = 0.f;
        F4(0, am0, ad0) F4(1, am1, ad1)
        F4(2, am0, ad0) F4(3, am1, ad1)
        F4(4, am0, ad0) F4(5, am1, ad1)
        if (u < 4) { F4(6, am0, ad0) }

        float s_ = fmaf(-0.98f, am0 + am1, -0.02f * (ad0 + ad1));
        s_ += __shfl_xor(s_, 1);
        s_ += __shfl_xor(s_, 2);
        s_ += __shfl_xor(s_, 4);
        s_ += __shfl_xor(s_, 8);

        if (u == 0 && cand < NCAND)
            out[(size_t)b * NCAND + cand] = base + s_;
    }
#undef F4
#undef E
}

extern "C" void kernel_launch(void* const* d_in, const int* in_sizes, int n_in,
                              void* d_out, int out_size, void* d_ws, size_t ws_size,
                              hipStream_t stream) {
    const float* ent   = (const float*)d_in[0];
    const float* relc  = (const float*)d_in[1];
    const float* relo  = (const float*)d_in[2];
    const float* onev  = (const float*)d_in[3];
    const int*   pairs = (const int*)d_in[4];
    const int*   cidx  = (const int*)d_in[5];
    float*       out   = (float*)d_out;

    const size_t denB = (size_t)DROWS * DIM * 2;     // 11,648,000 B
    const size_t qB   = (size_t)1600 * 16;           // 25,600 B per table
    const size_t need = denB + 2 * qB + B * sizeof(float);

    if (ws_size >= need) {
        unsigned char* w = (unsigned char*)d_ws;
        uint4* dense16 = (uint4*)w;
        uint4* q16t    = (uint4*)(w + denB);
        uint4* o16t    = (uint4*)(w + denB + qB);
        float* baseg   = (float*)(w + denB + 2 * qB);

        setup_kernel<<<CVTBLK + B, THREADS, 0, stream>>>(
            ent, relc, relo, onev, pairs, cidx, dense16, q16t, o16t, baseg);
        score_f16<<<SBLOCKS, THREADS, 0, stream>>>(
            dense16, q16t, o16t, baseg, out);
    } else {
        score_f32<<<8 * 8 * 32, THREADS, 0, stream>>>(
            ent, relc, relo, onev, pairs, cidx, out);
    }
}